// Round 3
// baseline (504.096 us; speedup 1.0000x reference)
//
#include <hip/hip_runtime.h>
#include <cstdint>
#include <cstddef>

#define ALPHA 0.01f
#define A1    0.99f
#define B_    8
#define S_    2048
#define H_    2048
#define NCH   8      // chunks along S
#define CL    256    // chunk length
#define NKT   32     // K tiles in GEMM (2048/64)

typedef __attribute__((ext_vector_type(8))) short bf16x8;
typedef __attribute__((ext_vector_type(4))) float f32x4;

__device__ __forceinline__ unsigned short f2bf(float f) {
    unsigned int u = __float_as_uint(f);
    u += 0x7FFFu + ((u >> 16) & 1u);   // round-to-nearest-even
    return (unsigned short)(u >> 16);
}

__device__ __forceinline__ void gld16(const void* g, void* l) {
    __builtin_amdgcn_global_load_lds(
        (const __attribute__((address_space(1))) unsigned int*)g,
        (__attribute__((address_space(3))) unsigned int*)l, 16, 0, 0);
}

// ---------------- W cast: f32 -> bf16 (+ flag clear for scan kernel) --------
__global__ void ema_cast_w(const float* __restrict__ W, short* __restrict__ Wb,
                           int* __restrict__ flags) {
    if (blockIdx.x == 0) {
        flags[threadIdx.x] = 0;
        flags[threadIdx.x + 256] = 0;
    }
    int i = (blockIdx.x * 256 + threadIdx.x) * 4;
    float4 v = *(const float4*)(W + i);
    short4 o;
    o.x = (short)f2bf(v.x);
    o.y = (short)f2bf(v.y);
    o.z = (short)f2bf(v.z);
    o.w = (short)f2bf(v.w);
    *(short4*)(Wb + i) = o;
}

// ---------------- single-pass EMA scan with decoupled lookback --------------
// block (b,c,hg): 256 threads, thread owns column h. Chain per (b,hg) over c.
// flags[(b*8+c)*8+hg] = 1 once carryInc[b][c][:] is globally visible.
__global__ __launch_bounds__(256) void ema_scan_kernel(
        const float* __restrict__ x, unsigned short* __restrict__ sb,
        float* __restrict__ carryInc, int* __restrict__ flags) {
    int bid = blockIdx.x;
    int c  = bid >> 6;          // slowest-varying: low-c blocks dispatch first
    int b  = (bid >> 3) & 7;
    int hg = bid & 7;
    int h  = (hg << 8) + threadIdx.x;
    size_t base = ((size_t)(b * S_) + (size_t)c * CL) * H_ + h;
    const float* px = x + base;
    unsigned short* ps = sb + base;

    float A256 = A1;                 // 0.99^256 via 8 squarings
    #pragma unroll
    for (int q = 0; q < 8; ++q) A256 *= A256;

    if (c == 0) {
        float s = px[0];             // t=0 carries full weight
        ps[0] = f2bf(s);
        #pragma unroll 8
        for (int i = 1; i < CL; ++i) {
            s = fmaf(A1, s, ALPHA * px[(size_t)i * H_]);
            ps[(size_t)i * H_] = f2bf(s);
        }
        carryInc[((b << 3) + 0) * H_ + h] = s;
        __threadfence();
        __syncthreads();
        if (threadIdx.x == 0)
            __hip_atomic_store(&flags[((b << 3) << 3) | hg], 1,
                               __ATOMIC_RELEASE, __HIP_MEMORY_SCOPE_AGENT);
        return;
    }

    // phase A: chunk-local carry (zero carry-in). Chunk 7's carry is dead.
    float loc = 0.f;
    if (c < 7) {
        #pragma unroll 8
        for (int i = 0; i < CL; ++i)
            loc = fmaf(A1, loc, ALPHA * px[(size_t)i * H_]);
    }

    // wait for predecessor's inclusive carry
    int pf = (((b << 3) + (c - 1)) << 3) | hg;
    if (threadIdx.x == 0) {
        while (__hip_atomic_load(&flags[pf], __ATOMIC_ACQUIRE,
                                 __HIP_MEMORY_SCOPE_AGENT) == 0)
            __builtin_amdgcn_s_sleep(4);
    }
    __syncthreads();
    float prev = __hip_atomic_load(&carryInc[((b << 3) + (c - 1)) * H_ + h],
                                   __ATOMIC_RELAXED, __HIP_MEMORY_SCOPE_AGENT);

    if (c < 7) {   // publish inclusive carry ASAP, before the local rescan
        float inc = fmaf(A256, prev, loc);
        carryInc[((b << 3) + c) * H_ + h] = inc;
        __threadfence();
        __syncthreads();
        if (threadIdx.x == 0)
            __hip_atomic_store(&flags[(((b << 3) + c) << 3) | hg], 1,
                               __ATOMIC_RELEASE, __HIP_MEMORY_SCOPE_AGENT);
    }

    // phase B: rescan with true carry-in, write bf16 s (x re-read is L2-warm)
    float s = prev;
    #pragma unroll 8
    for (int i = 0; i < CL; ++i) {
        s = fmaf(A1, s, ALPHA * px[(size_t)i * H_]);
        ps[(size_t)i * H_] = f2bf(s);
    }
}

// ---------------- GEMM: 256x256 tile, BK=64, 8 waves, 8-phase counted-vmcnt ----
// out[m,n] = sum_k s[m,k]*W[n,k] + bias[n].  M=16384 N=2048 K=2048.
// LDS 128 KiB: A,B double-buffered 256x64 bf16 tiles.
// Stage tile t+2 into cur's dead quarters (ph1: A1st+B1st, ph2: B2nd, ph3: A2nd);
// ONE vmcnt(8) per tile at ph3-end forces tile t+1's batch (>=4 phases slack).
// Swizzle: byte ^= ((storage_row & 7) << 4); both-sides (pre-swizzled global
// source for linear global_load_lds + swizzled ds_read address).

#define BAR __builtin_amdgcn_s_barrier()
#define WAIT_LGKM do { asm volatile("s_waitcnt lgkmcnt(0)" ::: "memory"); \
                       __builtin_amdgcn_sched_barrier(0); } while (0)
#define VMW(n) asm volatile("s_waitcnt vmcnt(" #n ")" ::: "memory")

#define STGA(i, kt, buf) gld16(gA[i] + (size_t)(kt) * 128, &ldsA[buf][((i) << 12) + (w << 9)])
#define STGB(i, kt, buf) gld16(gB[i] + (size_t)(kt) * 128, &ldsB[buf][((i) << 12) + (w << 9)])

#define LDA(mh) do { int ra_ = (wm << 1) | (mh);                                   \
    const char* base_ = (const char*)&ldsA[cur][0]                                 \
        + (((((ra_ & 1) << 1) | (ra_ >> 1))) << 13) + laneRow;                     \
    _Pragma("unroll") for (int m_ = 0; m_ < 4; ++m_) {                             \
        Af[m_][0] = *(const bf16x8*)(base_ + (m_ << 11) + ck0);                    \
        Af[m_][1] = *(const bf16x8*)(base_ + (m_ << 11) + ck1); } } while (0)

#define LDB(nh) do { const char* base_ = (const char*)&ldsB[cur][0]                \
        + ((nh) << 14) + (wn << 12) + laneRow;                                     \
    _Pragma("unroll") for (int n_ = 0; n_ < 2; ++n_) {                             \
        Bf[(nh) * 2 + n_][0] = *(const bf16x8*)(base_ + (n_ << 11) + ck0);         \
        Bf[(nh) * 2 + n_][1] = *(const bf16x8*)(base_ + (n_ << 11) + ck1); } } while (0)

#define MM(mh, nh) do { __builtin_amdgcn_s_setprio(1);                             \
    _Pragma("unroll") for (int m_ = 0; m_ < 4; ++m_)                               \
    _Pragma("unroll") for (int n_ = 0; n_ < 2; ++n_)                               \
    _Pragma("unroll") for (int k_ = 0; k_ < 2; ++k_)                               \
        acc[(mh) * 4 + m_][(nh) * 2 + n_] = __builtin_amdgcn_mfma_f32_16x16x32_bf16( \
            Af[m_][k_], Bf[(nh) * 2 + n_][k_], acc[(mh) * 4 + m_][(nh) * 2 + n_], 0, 0, 0); \
    __builtin_amdgcn_s_setprio(0); } while (0)

__global__ __launch_bounds__(512, 2) void ema_gemm_kernel(
        const short* __restrict__ Sb, const short* __restrict__ Wb,
        const float* __restrict__ bias, float* __restrict__ out) {
    __shared__ short ldsA[2][16384];   // 64 KiB
    __shared__ short ldsB[2][16384];   // 64 KiB

    int bid = blockIdx.x;
    int swz = ((bid & 7) << 6) | (bid >> 3);   // XCD swizzle, bijective (512 % 8 == 0)
    int tm = swz >> 3;                 // 0..63
    int tn = swz & 7;                  // 0..7

    int tid  = threadIdx.x;
    int lane = tid & 63;
    int w    = tid >> 6;               // 0..7
    int wm   = w >> 2;                 // 0..1
    int wn   = w & 3;                  // 0..3

    const int K2 = H_ * 2;             // row stride in bytes (4096)
    int rowA = tm << 8;
    int rowB = tn << 8;

    // ---- staging source pointers (per-lane, pre-swizzled global addresses) ----
    int rowoff = (w << 3) + (lane >> 3);                 // 0..63 within an 8KB issue
    int colb   = (((lane & 7) ^ (lane >> 3)) << 4);      // inverse-swizzled k-byte
    const char* SbB = (const char*)Sb;
    const char* WbB = (const char*)Wb;
    const char* gA[4];
    const char* gB[4];
    #pragma unroll
    for (int i = 0; i < 4; ++i) {
        int lq = ((i & 1) << 1) | (i >> 1);              // storage slot -> logical A quarter
        gA[i] = SbB + (size_t)(rowA + lq * 64 + rowoff) * K2 + colb;
        int pos = 2 * i + (w >> 2);                      // B storage 32-row slot
        int ls  = ((pos & 3) << 1) | (pos >> 2);         // -> logical slice
        gB[i] = WbB + (size_t)(rowB + ls * 32 + ((w & 3) << 3) + (lane >> 3)) * K2 + colb;
    }

    // ---- fragment ds_read offsets (swizzled) ----
    int laneRow = (lane & 15) << 7;
    int ck0 = (((lane >> 4)) ^ (lane & 7)) << 4;
    int ck1 = ((4 + (lane >> 4)) ^ (lane & 7)) << 4;

    f32x4 acc[8][4];
    #pragma unroll
    for (int i = 0; i < 8; ++i)
        #pragma unroll
        for (int j = 0; j < 4; ++j)
            acc[i][j] = (f32x4){0.f, 0.f, 0.f, 0.f};
    bf16x8 Af[4][2], Bf[4][2];

    int colg = (tn << 8) + (wn << 6) + (lane & 15);
    float bb[4];
    #pragma unroll
    for (int n = 0; n < 4; ++n) bb[n] = bias[colg + (n << 4)];

    // ---- prologue: tiles 0 and 1 fully staged (16 loads); force tile 0 ----
    STGA(0, 0, 0); STGA(1, 0, 0); STGB(0, 0, 0); STGB(1, 0, 0);
    STGA(2, 0, 0); STGA(3, 0, 0); STGB(2, 0, 0); STGB(3, 0, 0);
    STGA(0, 1, 1); STGA(1, 1, 1); STGB(0, 1, 1); STGB(1, 1, 1);
    STGA(2, 1, 1); STGA(3, 1, 1); STGB(2, 1, 1); STGB(3, 1, 1);
    VMW(8);
    BAR;

    for (int t = 0; t < NKT; ++t) {
        int cur = t & 1;
        bool stg = (t < NKT - 2);
        // phase 0: compute (mh0,nh0); 12 ds_reads -> lgkm throttle per template
        LDA(0); LDB(0);
        asm volatile("s_waitcnt lgkmcnt(8)" ::: "memory");
        BAR; WAIT_LGKM;
        MM(0, 0);
        BAR;
        // phase 1: compute (mh0,nh1); stage A1st(t+2)+B1st(t+2) into dead cur
        LDB(1);
        if (stg) { STGA(0, t + 2, cur); STGA(1, t + 2, cur);
                   STGB(0, t + 2, cur); STGB(1, t + 2, cur); }
        BAR; WAIT_LGKM;
        MM(0, 1);
        BAR;
        // phase 2: compute (mh1,nh0); stage B2nd(t+2)
        LDA(1);
        if (stg) { STGB(2, t + 2, cur); STGB(3, t + 2, cur); }
        BAR; WAIT_LGKM;
        MM(1, 0);
        BAR;
        // phase 3: compute (mh1,nh1); stage A2nd(t+2); single per-tile vmcnt
        if (stg) { STGA(2, t + 2, cur); STGA(3, t + 2, cur); }
        BAR;
        MM(1, 1);
        if (t < NKT - 2)       { VMW(8); }   // forces tile t+1's 8-load batch
        else if (t == NKT - 2) { VMW(0); }   // drain for the last tile
        BAR;
    }

    // ---- epilogue: C/D layout col=lane&15, row=(lane>>4)*4+q ----
    int rowg = (tm << 8) + (wm << 7) + ((lane >> 4) << 2);
    #pragma unroll
    for (int m = 0; m < 8; ++m) {
        #pragma unroll
        for (int n = 0; n < 4; ++n) {
            int c = colg + (n << 4);
            size_t rb = (size_t)(rowg + (m << 4)) << 11;
            #pragma unroll
            for (int q = 0; q < 4; ++q)
                out[rb + ((size_t)q << 11) + c] = acc[m][n][q] + bb[n];
        }
    }
}

extern "C" void kernel_launch(void* const* d_in, const int* in_sizes, int n_in,
                              void* d_out, int out_size, void* d_ws, size_t ws_size,
                              hipStream_t stream) {
    const float* x    = (const float*)d_in[0];   // [B,S,H] f32
    const float* W    = (const float*)d_in[1];   // [H,H] f32
    const float* bias = (const float*)d_in[2];   // [H] f32
    float* out = (float*)d_out;                  // [B,S,H] f32

    char* ws = (char*)d_ws;
    size_t s_bytes = (size_t)B_ * S_ * H_ * 2;   // 67.1 MB bf16 s
    size_t w_bytes = (size_t)H_ * H_ * 2;        // 8.4 MB bf16 W
    size_t c_bytes = (size_t)B_ * NCH * H_ * 4;  // 512 KB inclusive carries
    unsigned short* s_bf  = (unsigned short*)ws;
    short*          w_bf  = (short*)(ws + s_bytes);
    float*          carry = (float*)(ws + s_bytes + w_bytes);
    int*            flags = (int*)(ws + s_bytes + w_bytes + c_bytes);  // 512 ints

    ema_cast_w<<<(H_ * H_) / 1024, 256, 0, stream>>>(W, w_bf, flags);
    ema_scan_kernel<<<B_ * NCH * (H_ / 256), 256, 0, stream>>>(x, s_bf, carry, flags);
    ema_gemm_kernel<<<(16384 / 256) * (2048 / 256), 512, 0, stream>>>(
        (const short*)s_bf, w_bf, bias, out);
}

// Round 4
// 231.590 us; speedup vs baseline: 2.1767x; 2.1767x over previous
//
#include <hip/hip_runtime.h>
#include <cstdint>
#include <cstddef>

#define ALPHA 0.01f
#define A1    0.99f
#define B_    8
#define S_    2048
#define H_    2048
#define NCH   8      // chunks along S
#define CL    256    // chunk length
#define NKT   32     // K tiles in GEMM (2048/64)

typedef __attribute__((ext_vector_type(8))) short bf16x8;
typedef __attribute__((ext_vector_type(4))) float f32x4;

__device__ __forceinline__ unsigned short f2bf(float f) {
    unsigned int u = __float_as_uint(f);
    u += 0x7FFFu + ((u >> 16) & 1u);   // round-to-nearest-even
    return (unsigned short)(u >> 16);
}

__device__ __forceinline__ void gld16(const void* g, void* l) {
    __builtin_amdgcn_global_load_lds(
        (const __attribute__((address_space(1))) unsigned int*)g,
        (__attribute__((address_space(3))) unsigned int*)l, 16, 0, 0);
}

// ---------------- W cast: f32 -> bf16 ----------------
__global__ void ema_cast_w(const float* __restrict__ W, short* __restrict__ Wb) {
    int i = (blockIdx.x * 256 + threadIdx.x) * 4;
    float4 v = *(const float4*)(W + i);
    short4 o;
    o.x = (short)f2bf(v.x);
    o.y = (short)f2bf(v.y);
    o.z = (short)f2bf(v.z);
    o.w = (short)f2bf(v.w);
    *(short4*)(Wb + i) = o;
}

// ---------------- pass 1: chunk-local EMA carries ----------------
__global__ __launch_bounds__(256) void ema_carry_kernel(
        const float* __restrict__ x, float* __restrict__ carry) {
    int bid = blockIdx.x;
    int hg = bid & 7;
    int c  = (bid >> 3) & 7;
    int b  = bid >> 6;
    int h  = hg * 256 + threadIdx.x;
    const float* px = x + ((size_t)(b * S_) + c * CL) * H_ + h;
    float s;
    int i0;
    if (c == 0) { s = px[0]; i0 = 1; }   // t=0 carries full weight
    else        { s = 0.f;   i0 = 0; }
    #pragma unroll 8
    for (int i = i0; i < CL; ++i)
        s = fmaf(A1, s, ALPHA * px[(size_t)i * H_]);
    carry[((b << 3) + c) * H_ + h] = s;
}

// ---------------- pass 2: apply carry-in, rescan, write bf16 s ----------------
__global__ __launch_bounds__(256) void ema_apply_kernel(
        const float* __restrict__ x, const float* __restrict__ carry,
        unsigned short* __restrict__ sb) {
    int bid = blockIdx.x;
    int hg = bid & 7;
    int c  = (bid >> 3) & 7;
    int b  = bid >> 6;
    int h  = hg * 256 + threadIdx.x;

    float A256 = A1;                 // 0.99^(2^8) after 8 squarings
    #pragma unroll
    for (int q = 0; q < 8; ++q) A256 *= A256;

    float ci = 0.f, f = 1.f;
    for (int j = c - 1; j >= 0; --j) {
        ci = fmaf(carry[((b << 3) + j) * H_ + h], f, ci);
        f *= A256;
    }

    size_t base = ((size_t)(b * S_) + c * CL) * H_ + h;
    const float* px = x + base;
    unsigned short* ps = sb + base;
    float s;
    int i0;
    if (c == 0) { s = px[0]; ps[0] = f2bf(s); i0 = 1; }
    else        { s = ci;    i0 = 0; }
    #pragma unroll 8
    for (int i = i0; i < CL; ++i) {
        s = fmaf(A1, s, ALPHA * px[(size_t)i * H_]);
        ps[(size_t)i * H_] = f2bf(s);
    }
}

// ---------------- GEMM: 256x256 tile, BK=64, 8 waves, 8-phase counted-vmcnt ----
// out[m,n] = sum_k s[m,k]*W[n,k] + bias[n].  M=16384 N=2048 K=2048.
// LDS 128 KiB: A,B double-buffered 256x64 bf16 tiles.
// Stage tile t+2 into cur's dead quarters (ph1: A1st+B1st, ph2: B2nd, ph3: A2nd);
// ONE vmcnt(8) per tile at ph3-end forces tile t+1's batch (>=4 phases slack).
// Swizzle: byte ^= ((storage_row & 7) << 4); both-sides (pre-swizzled global
// source for linear global_load_lds + swizzled ds_read address).

#define BAR __builtin_amdgcn_s_barrier()
#define WAIT_LGKM do { asm volatile("s_waitcnt lgkmcnt(0)" ::: "memory"); \
                       __builtin_amdgcn_sched_barrier(0); } while (0)
#define VMW(n) asm volatile("s_waitcnt vmcnt(" #n ")" ::: "memory")

#define STGA(i, kt, buf) gld16(gA[i] + (size_t)(kt) * 128, &ldsA[buf][((i) << 12) + (w << 9)])
#define STGB(i, kt, buf) gld16(gB[i] + (size_t)(kt) * 128, &ldsB[buf][((i) << 12) + (w << 9)])

#define LDA(mh) do { int ra_ = (wm << 1) | (mh);                                   \
    const char* base_ = (const char*)&ldsA[cur][0]                                 \
        + (((((ra_ & 1) << 1) | (ra_ >> 1))) << 13) + laneRow;                     \
    _Pragma("unroll") for (int m_ = 0; m_ < 4; ++m_) {                             \
        Af[m_][0] = *(const bf16x8*)(base_ + (m_ << 11) + ck0);                    \
        Af[m_][1] = *(const bf16x8*)(base_ + (m_ << 11) + ck1); } } while (0)

#define LDB(nh) do { const char* base_ = (const char*)&ldsB[cur][0]                \
        + ((nh) << 14) + (wn << 12) + laneRow;                                     \
    _Pragma("unroll") for (int n_ = 0; n_ < 2; ++n_) {                             \
        Bf[(nh) * 2 + n_][0] = *(const bf16x8*)(base_ + (n_ << 11) + ck0);         \
        Bf[(nh) * 2 + n_][1] = *(const bf16x8*)(base_ + (n_ << 11) + ck1); } } while (0)

#define MM(mh, nh) do { __builtin_amdgcn_s_setprio(1);                             \
    _Pragma("unroll") for (int m_ = 0; m_ < 4; ++m_)                               \
    _Pragma("unroll") for (int n_ = 0; n_ < 2; ++n_)                               \
    _Pragma("unroll") for (int k_ = 0; k_ < 2; ++k_)                               \
        acc[(mh) * 4 + m_][(nh) * 2 + n_] = __builtin_amdgcn_mfma_f32_16x16x32_bf16( \
            Af[m_][k_], Bf[(nh) * 2 + n_][k_], acc[(mh) * 4 + m_][(nh) * 2 + n_], 0, 0, 0); \
    __builtin_amdgcn_s_setprio(0); } while (0)

__global__ __launch_bounds__(512, 2) void ema_gemm_kernel(
        const short* __restrict__ Sb, const short* __restrict__ Wb,
        const float* __restrict__ bias, float* __restrict__ out) {
    __shared__ short ldsA[2][16384];   // 64 KiB
    __shared__ short ldsB[2][16384];   // 64 KiB

    int bid = blockIdx.x;
    int swz = ((bid & 7) << 6) | (bid >> 3);   // XCD swizzle, bijective (512 % 8 == 0)
    int tm = swz >> 3;                 // 0..63
    int tn = swz & 7;                  // 0..7

    int tid  = threadIdx.x;
    int lane = tid & 63;
    int w    = tid >> 6;               // 0..7
    int wm   = w >> 2;                 // 0..1
    int wn   = w & 3;                  // 0..3

    const int K2 = H_ * 2;             // row stride in bytes (4096)
    int rowA = tm << 8;
    int rowB = tn << 8;

    // ---- staging source pointers (per-lane, pre-swizzled global addresses) ----
    int rowoff = (w << 3) + (lane >> 3);                 // 0..63 within an 8KB issue
    int colb   = (((lane & 7) ^ (lane >> 3)) << 4);      // inverse-swizzled k-byte
    const char* SbB = (const char*)Sb;
    const char* WbB = (const char*)Wb;
    const char* gA[4];
    const char* gB[4];
    #pragma unroll
    for (int i = 0; i < 4; ++i) {
        int lq = ((i & 1) << 1) | (i >> 1);              // storage slot -> logical A quarter
        gA[i] = SbB + (size_t)(rowA + lq * 64 + rowoff) * K2 + colb;
        int pos = 2 * i + (w >> 2);                      // B storage 32-row slot
        int ls  = ((pos & 3) << 1) | (pos >> 2);         // -> logical slice
        gB[i] = WbB + (size_t)(rowB + ls * 32 + ((w & 3) << 3) + (lane >> 3)) * K2 + colb;
    }

    // ---- fragment ds_read offsets (swizzled) ----
    int laneRow = (lane & 15) << 7;
    int ck0 = (((lane >> 4)) ^ (lane & 7)) << 4;
    int ck1 = ((4 + (lane >> 4)) ^ (lane & 7)) << 4;

    f32x4 acc[8][4];
    #pragma unroll
    for (int i = 0; i < 8; ++i)
        #pragma unroll
        for (int j = 0; j < 4; ++j)
            acc[i][j] = (f32x4){0.f, 0.f, 0.f, 0.f};
    bf16x8 Af[4][2], Bf[4][2];

    int colg = (tn << 8) + (wn << 6) + (lane & 15);
    float bb[4];
    #pragma unroll
    for (int n = 0; n < 4; ++n) bb[n] = bias[colg + (n << 4)];

    // ---- prologue: tiles 0 and 1 fully staged (16 loads); force tile 0 ----
    STGA(0, 0, 0); STGA(1, 0, 0); STGB(0, 0, 0); STGB(1, 0, 0);
    STGA(2, 0, 0); STGA(3, 0, 0); STGB(2, 0, 0); STGB(3, 0, 0);
    STGA(0, 1, 1); STGA(1, 1, 1); STGB(0, 1, 1); STGB(1, 1, 1);
    STGA(2, 1, 1); STGA(3, 1, 1); STGB(2, 1, 1); STGB(3, 1, 1);
    VMW(8);
    BAR;

    for (int t = 0; t < NKT; ++t) {
        int cur = t & 1;
        bool stg = (t < NKT - 2);
        // phase 0: compute (mh0,nh0); 12 ds_reads -> lgkm throttle per template
        LDA(0); LDB(0);
        asm volatile("s_waitcnt lgkmcnt(8)" ::: "memory");
        BAR; WAIT_LGKM;
        MM(0, 0);
        BAR;
        // phase 1: compute (mh0,nh1); stage A1st(t+2)+B1st(t+2) into dead cur
        LDB(1);
        if (stg) { STGA(0, t + 2, cur); STGA(1, t + 2, cur);
                   STGB(0, t + 2, cur); STGB(1, t + 2, cur); }
        BAR; WAIT_LGKM;
        MM(0, 1);
        BAR;
        // phase 2: compute (mh1,nh0); stage B2nd(t+2)
        LDA(1);
        if (stg) { STGB(2, t + 2, cur); STGB(3, t + 2, cur); }
        BAR; WAIT_LGKM;
        MM(1, 0);
        BAR;
        // phase 3: compute (mh1,nh1); stage A2nd(t+2); single per-tile vmcnt
        if (stg) { STGA(2, t + 2, cur); STGA(3, t + 2, cur); }
        BAR;
        MM(1, 1);
        if (t < NKT - 2)       { VMW(8); }   // forces tile t+1's 8-load batch
        else if (t == NKT - 2) { VMW(0); }   // drain for the last tile
        BAR;
    }

    // ---- epilogue: C/D layout col=lane&15, row=(lane>>4)*4+q ----
    int rowg = (tm << 8) + (wm << 7) + ((lane >> 4) << 2);
    #pragma unroll
    for (int m = 0; m < 8; ++m) {
        #pragma unroll
        for (int n = 0; n < 4; ++n) {
            int c = colg + (n << 4);
            size_t rb = (size_t)(rowg + (m << 4)) << 11;
            #pragma unroll
            for (int q = 0; q < 4; ++q)
                out[rb + ((size_t)q << 11) + c] = acc[m][n][q] + bb[n];
        }
    }
}

extern "C" void kernel_launch(void* const* d_in, const int* in_sizes, int n_in,
                              void* d_out, int out_size, void* d_ws, size_t ws_size,
                              hipStream_t stream) {
    const float* x    = (const float*)d_in[0];   // [B,S,H] f32
    const float* W    = (const float*)d_in[1];   // [H,H] f32
    const float* bias = (const float*)d_in[2];   // [H] f32
    float* out = (float*)d_out;                  // [B,S,H] f32

    char* ws = (char*)d_ws;
    size_t s_bytes = (size_t)B_ * S_ * H_ * 2;   // 67.1 MB bf16 s
    size_t w_bytes = (size_t)H_ * H_ * 2;        // 8.4 MB bf16 W
    unsigned short* s_bf  = (unsigned short*)ws;
    short*          w_bf  = (short*)(ws + s_bytes);
    float*          carry = (float*)(ws + s_bytes + w_bytes);  // 8*8*2048 f32

    ema_cast_w<<<(H_ * H_) / 1024, 256, 0, stream>>>(W, w_bf);
    ema_carry_kernel<<<B_ * NCH * (H_ / 256), 256, 0, stream>>>(x, carry);
    ema_apply_kernel<<<B_ * NCH * (H_ / 256), 256, 0, stream>>>(x, carry, s_bf);
    ema_gemm_kernel<<<(16384 / 256) * (2048 / 256), 512, 0, stream>>>(
        (const short*)s_bf, w_bf, bias, out);
}

// Round 5
// 191.471 us; speedup vs baseline: 2.6328x; 1.2095x over previous
//
#include <hip/hip_runtime.h>
#include <cstdint>
#include <cstddef>

#define ALPHA 0.01f
#define A1    0.99f
#define B_    8
#define S_    2048
#define H_    2048
#define NCH   8      // chunks along S
#define CL    256    // chunk length
#define NKT   32     // K tiles in GEMM (2048/64)

typedef __attribute__((ext_vector_type(8))) short bf16x8;
typedef __attribute__((ext_vector_type(4))) float f32x4;

__device__ __forceinline__ unsigned short f2bf(float f) {
    unsigned int u = __float_as_uint(f);
    u += 0x7FFFu + ((u >> 16) & 1u);   // round-to-nearest-even
    return (unsigned short)(u >> 16);
}

__device__ __forceinline__ void gld16(const void* g, void* l) {
    __builtin_amdgcn_global_load_lds(
        (const __attribute__((address_space(1))) unsigned int*)g,
        (__attribute__((address_space(3))) unsigned int*)l, 16, 0, 0);
}

// ---------------- W cast: f32 -> bf16 ----------------
__global__ void ema_cast_w(const float* __restrict__ W, short* __restrict__ Wb) {
    int i = (blockIdx.x * 256 + threadIdx.x) * 4;
    float4 v = *(const float4*)(W + i);
    short4 o;
    o.x = (short)f2bf(v.x);
    o.y = (short)f2bf(v.y);
    o.z = (short)f2bf(v.z);
    o.w = (short)f2bf(v.w);
    *(short4*)(Wb + i) = o;
}

// ---------------- pass 1: chunk-local EMA carries (float2, 2 chains/thread) ----
__global__ __launch_bounds__(256) void ema_carry_kernel(
        const float* __restrict__ x, float* __restrict__ carry) {
    int bid = blockIdx.x;                 // 256 blocks: b(8) x c(8) x hg(4)
    int hg = bid & 3;
    int c  = (bid >> 2) & 7;
    int b  = bid >> 5;
    int h0 = (hg << 9) + (threadIdx.x << 1);
    const float2* px = (const float2*)(x + ((size_t)(b * S_) + (size_t)c * CL) * H_ + h0);
    const int STR = H_ / 2;               // float2 stride per sequence step
    float s0, s1;
    int i0;
    if (c == 0) { float2 v = px[0]; s0 = v.x; s1 = v.y; i0 = 1; }
    else        { s0 = 0.f; s1 = 0.f;                   i0 = 0; }
    #pragma unroll 8
    for (int i = i0; i < CL; ++i) {
        float2 v = px[(size_t)i * STR];
        s0 = fmaf(A1, s0, ALPHA * v.x);
        s1 = fmaf(A1, s1, ALPHA * v.y);
    }
    *(float2*)(carry + ((b << 3) + c) * H_ + h0) = (float2){s0, s1};
}

// ---------------- pass 2: apply carry-in, rescan, write packed bf16 s ----------
__global__ __launch_bounds__(256) void ema_apply_kernel(
        const float* __restrict__ x, const float* __restrict__ carry,
        unsigned short* __restrict__ sb) {
    int bid = blockIdx.x;                 // 256 blocks: b(8) x c(8) x hg(4)
    int hg = bid & 3;
    int c  = (bid >> 2) & 7;
    int b  = bid >> 5;
    int h0 = (hg << 9) + (threadIdx.x << 1);

    float A256 = A1;                      // 0.99^256 via 8 squarings
    #pragma unroll
    for (int q = 0; q < 8; ++q) A256 *= A256;

    float c0 = 0.f, c1 = 0.f, f = 1.f;
    for (int j = c - 1; j >= 0; --j) {
        float2 cv = *(const float2*)(carry + ((b << 3) + j) * H_ + h0);
        c0 = fmaf(cv.x, f, c0);
        c1 = fmaf(cv.y, f, c1);
        f *= A256;
    }

    size_t base = ((size_t)(b * S_) + (size_t)c * CL) * H_ + h0;
    const float2* px = (const float2*)(x + base);
    unsigned int*  pu = (unsigned int*)(sb + base);
    const int STR = H_ / 2;
    float s0, s1;
    int i0;
    if (c == 0) {
        float2 v = px[0]; s0 = v.x; s1 = v.y;
        pu[0] = (unsigned int)f2bf(s0) | ((unsigned int)f2bf(s1) << 16);
        i0 = 1;
    } else { s0 = c0; s1 = c1; i0 = 0; }
    #pragma unroll 8
    for (int i = i0; i < CL; ++i) {
        float2 v = px[(size_t)i * STR];
        s0 = fmaf(A1, s0, ALPHA * v.x);
        s1 = fmaf(A1, s1, ALPHA * v.y);
        pu[(size_t)i * STR] = (unsigned int)f2bf(s0) | ((unsigned int)f2bf(s1) << 16);
    }
}

// ---------------- GEMM: 256x256 tile, BK=64, 8 waves, 8-phase counted-vmcnt ----
// out[m,n] = sum_k s[m,k]*W[n,k] + bias[n].  M=16384 N=2048 K=2048.
// ROUND-2 SCHEDULE (A/B-proven best: 146 vs 162 us for the single-VMW(8) variant).
// LDS 128 KiB: A,B double-buffered 256x64 bf16 tiles.
// Swizzle: byte ^= ((storage_row & 7) << 4); both-sides (pre-swizzled global
// source for linear global_load_lds + swizzled ds_read address).

#define BAR __builtin_amdgcn_s_barrier()
#define WAIT_LGKM do { asm volatile("s_waitcnt lgkmcnt(0)" ::: "memory"); \
                       __builtin_amdgcn_sched_barrier(0); } while (0)
#define VMW(n) asm volatile("s_waitcnt vmcnt(" #n ")" ::: "memory")

#define STGA(i, kt, buf) gld16(gA[i] + (size_t)(kt) * 128, &ldsA[buf][((i) << 12) + (w << 9)])
#define STGB(i, kt, buf) gld16(gB[i] + (size_t)(kt) * 128, &ldsB[buf][((i) << 12) + (w << 9)])

#define LDA(mh) do { int ra_ = (wm << 1) | (mh);                                   \
    const char* base_ = (const char*)&ldsA[cur][0]                                 \
        + (((((ra_ & 1) << 1) | (ra_ >> 1))) << 13) + laneRow;                     \
    _Pragma("unroll") for (int m_ = 0; m_ < 4; ++m_) {                             \
        Af[m_][0] = *(const bf16x8*)(base_ + (m_ << 11) + ck0);                    \
        Af[m_][1] = *(const bf16x8*)(base_ + (m_ << 11) + ck1); } } while (0)

#define LDB(nh) do { const char* base_ = (const char*)&ldsB[cur][0]                \
        + ((nh) << 14) + (wn << 12) + laneRow;                                     \
    _Pragma("unroll") for (int n_ = 0; n_ < 2; ++n_) {                             \
        Bf[(nh) * 2 + n_][0] = *(const bf16x8*)(base_ + (n_ << 11) + ck0);         \
        Bf[(nh) * 2 + n_][1] = *(const bf16x8*)(base_ + (n_ << 11) + ck1); } } while (0)

#define MM(mh, nh) do { __builtin_amdgcn_s_setprio(1);                             \
    _Pragma("unroll") for (int m_ = 0; m_ < 4; ++m_)                               \
    _Pragma("unroll") for (int n_ = 0; n_ < 2; ++n_)                               \
    _Pragma("unroll") for (int k_ = 0; k_ < 2; ++k_)                               \
        acc[(mh) * 4 + m_][(nh) * 2 + n_] = __builtin_amdgcn_mfma_f32_16x16x32_bf16( \
            Af[m_][k_], Bf[(nh) * 2 + n_][k_], acc[(mh) * 4 + m_][(nh) * 2 + n_], 0, 0, 0); \
    __builtin_amdgcn_s_setprio(0); } while (0)

__global__ __launch_bounds__(512, 2) void ema_gemm_kernel(
        const short* __restrict__ Sb, const short* __restrict__ Wb,
        const float* __restrict__ bias, float* __restrict__ out) {
    __shared__ short ldsA[2][16384];   // 64 KiB
    __shared__ short ldsB[2][16384];   // 64 KiB

    int bid = blockIdx.x;
    int swz = ((bid & 7) << 6) | (bid >> 3);   // XCD swizzle, bijective (512 % 8 == 0)
    int tm = swz >> 3;                 // 0..63
    int tn = swz & 7;                  // 0..7

    int tid  = threadIdx.x;
    int lane = tid & 63;
    int w    = tid >> 6;               // 0..7
    int wm   = w >> 2;                 // 0..1
    int wn   = w & 3;                  // 0..3

    const int K2 = H_ * 2;             // row stride in bytes (4096)
    int rowA = tm << 8;
    int rowB = tn << 8;

    // ---- staging source pointers (per-lane, pre-swizzled global addresses) ----
    int rowoff = (w << 3) + (lane >> 3);                 // 0..63 within an 8KB issue
    int colb   = (((lane & 7) ^ (lane >> 3)) << 4);      // inverse-swizzled k-byte
    const char* SbB = (const char*)Sb;
    const char* WbB = (const char*)Wb;
    const char* gA[4];
    const char* gB[4];
    #pragma unroll
    for (int i = 0; i < 4; ++i) {
        int lq = ((i & 1) << 1) | (i >> 1);              // storage slot -> logical A quarter
        gA[i] = SbB + (size_t)(rowA + lq * 64 + rowoff) * K2 + colb;
        int pos = 2 * i + (w >> 2);                      // B storage 32-row slot
        int ls  = ((pos & 3) << 1) | (pos >> 2);         // -> logical slice
        gB[i] = WbB + (size_t)(rowB + ls * 32 + ((w & 3) << 3) + (lane >> 3)) * K2 + colb;
    }

    // ---- fragment ds_read offsets (swizzled) ----
    int laneRow = (lane & 15) << 7;
    int ck0 = (((lane >> 4)) ^ (lane & 7)) << 4;
    int ck1 = ((4 + (lane >> 4)) ^ (lane & 7)) << 4;

    f32x4 acc[8][4];
    #pragma unroll
    for (int i = 0; i < 8; ++i)
        #pragma unroll
        for (int j = 0; j < 4; ++j)
            acc[i][j] = (f32x4){0.f, 0.f, 0.f, 0.f};
    bf16x8 Af[4][2], Bf[4][2];

    int colg = (tn << 8) + (wn << 6) + (lane & 15);
    float bb[4];
    #pragma unroll
    for (int n = 0; n < 4; ++n) bb[n] = bias[colg + (n << 4)];

    // ---- prologue: tile0 full + tile1 first halves; leave 6 loads in flight ----
    STGA(0, 0, 0); STGA(1, 0, 0); STGB(0, 0, 0); STGB(1, 0, 0);   // A1st(0), B1st(0)
    STGA(2, 0, 0); STGA(3, 0, 0); STGB(2, 0, 0); STGB(3, 0, 0);   // A2nd(0), B2nd(0)
    STGA(0, 1, 1); STGA(1, 1, 1); STGB(0, 1, 1); STGB(1, 1, 1);   // A1st(1), B1st(1)
    VMW(6);
    BAR;

    for (int t = 0; t < NKT; ++t) {
        int cur = t & 1, nxt = cur ^ 1;
        bool i01 = (t < NKT - 1), i23 = (t < NKT - 2);
        // phase 0: compute (mh0,nh0); stage A2nd(t+1)
        LDA(0); LDB(0);
        if (i01) { STGA(2, t + 1, nxt); STGA(3, t + 1, nxt); }
        BAR; WAIT_LGKM;
        MM(0, 0);
        if (i01) { VMW(6); }
        BAR;
        // phase 1: compute (mh0,nh1); stage B2nd(t+1)
        LDB(1);
        if (i01) { STGB(2, t + 1, nxt); STGB(3, t + 1, nxt); }
        BAR; WAIT_LGKM;
        MM(0, 1);
        BAR;
        // phase 2: compute (mh1,nh0); stage A1st(t+2) into dead quarters of cur
        LDA(1);
        if (i23) { STGA(0, t + 2, cur); STGA(1, t + 2, cur); }
        BAR; WAIT_LGKM;
        MM(1, 0);
        BAR;
        // phase 3: compute (mh1,nh1); stage B1st(t+2) into dead slices of cur
        if (i23) { STGB(0, t + 2, cur); STGB(1, t + 2, cur); }
        BAR;
        MM(1, 1);
        if (t == NKT - 2) { VMW(0); }          // entering last tile: drain
        else if (t < NKT - 2) { VMW(6); }      // steady state: 3 half-tiles in flight
        BAR;
    }

    // ---- epilogue: C/D layout col=lane&15, row=(lane>>4)*4+q ----
    int rowg = (tm << 8) + (wm << 7) + ((lane >> 4) << 2);
    #pragma unroll
    for (int m = 0; m < 8; ++m) {
        #pragma unroll
        for (int n = 0; n < 4; ++n) {
            int c = colg + (n << 4);
            size_t rb = (size_t)(rowg + (m << 4)) << 11;
            #pragma unroll
            for (int q = 0; q < 4; ++q)
                out[rb + ((size_t)q << 11) + c] = acc[m][n][q] + bb[n];
        }
    }
}

extern "C" void kernel_launch(void* const* d_in, const int* in_sizes, int n_in,
                              void* d_out, int out_size, void* d_ws, size_t ws_size,
                              hipStream_t stream) {
    const float* x    = (const float*)d_in[0];   // [B,S,H] f32
    const float* W    = (const float*)d_in[1];   // [H,H] f32
    const float* bias = (const float*)d_in[2];   // [H] f32
    float* out = (float*)d_out;                  // [B,S,H] f32

    char* ws = (char*)d_ws;
    size_t s_bytes = (size_t)B_ * S_ * H_ * 2;   // 67.1 MB bf16 s
    size_t w_bytes = (size_t)H_ * H_ * 2;        // 8.4 MB bf16 W
    unsigned short* s_bf  = (unsigned short*)ws;
    short*          w_bf  = (short*)(ws + s_bytes);
    float*          carry = (float*)(ws + s_bytes + w_bytes);  // 8*8*2048 f32

    ema_cast_w<<<(H_ * H_) / 1024, 256, 0, stream>>>(W, w_bf);
    ema_carry_kernel<<<B_ * NCH * (H_ / 512), 256, 0, stream>>>(x, carry);
    ema_apply_kernel<<<B_ * NCH * (H_ / 512), 256, 0, stream>>>(x, carry, s_bf);
    ema_gemm_kernel<<<(16384 / 256) * (2048 / 256), 512, 0, stream>>>(
        (const short*)s_bf, w_bf, bias, out);
}